// Round 1
// 732.604 us; speedup vs baseline: 1.0129x; 1.0129x over previous
//
#include <hip/hip_runtime.h>

// Binary conv2d: x (8,16,1024,1024) fp32, w (16,16,3,3) in {0,1} decoded to
// +/-1, stride (2,2), pad (1,1) zeros => out (8,16,512,512) fp32.
//
// R3: 2x2-output-per-thread register-blocked variant.
// R2 (1 output/thread, launch_bounds(256,8), VGPR<=64) measured 742 us =
// ~12x the 61 us FMA-issue floor: the 64-VGPR cap forced a serial
// addr->load->vmcnt(0)->144fma pattern per ci with only 144 FMAs per
// 6-load stall window. Here each thread computes a 2x2 output patch:
//   - 5x5 input window = 5x float4 + 5x scalar = 10 loads per ci for 4
//     outputs (was 24), all behind ONE vmcnt wait,
//   - 576 FMAs per ci per thread (4x FMA density per stall window),
//   - each s_load'ed weight feeds 4 FMAs (was 1) -> 1/4 the lgkm waits
//     per FMA,
//   - float2 stores, 64 lanes x 8B fully coalesced.
// __launch_bounds__(256,4): 128 VGPR cap fits 64 acc + 25 xv + addressing
// (~110), 4 waves/SIMD hide L1/L2 latency under the 1152-cyc FMA blocks.

#define IN_H   1024
#define IN_W   1024
#define OUT_H  512
#define OUT_W  512
#define C_IN   16
#define C_OUT  16

// decode {0,1}->{+1,-1}, transpose OIHW -> [ci][tap][co] (co contiguous
// so per-(ci,tap) weights are an s_load_dwordx16 candidate).
__global__ void decode_weights(const float* __restrict__ w,
                               float* __restrict__ wdec) {
    int i = blockIdx.x * blockDim.x + threadIdx.x;   // 16*9*16 = 2304
    if (i >= C_IN * 9 * C_OUT) return;
    int co  = i & 15;
    int t   = i >> 4;        // ci*9 + tap
    int tap = t % 9;
    int ci  = t / 9;
    float v = w[(co * C_IN + ci) * 9 + tap];
    wdec[i] = (v == 1.0f) ? 1.0f : -1.0f;
}

__global__ __launch_bounds__(256, 4)
void binconv(const float* __restrict__ x,
             const float* __restrict__ wdec,
             float* __restrict__ out) {
    const int tx = threadIdx.x;                 // 0..63
    const int ty = threadIdx.y;                 // 0..3
    const int OW = blockIdx.x * 64 + tx;        // output col-PAIR index 0..255
    const int OH = blockIdx.y * 4 + ty;         // output row-PAIR index 0..255
    const int n  = blockIdx.z;                  // 0..7

    const float* xn = x + (size_t)n * C_IN * IN_H * IN_W;
    // 2x2 outputs at (2OH..2OH+1, 2OW..2OW+1) need input rows 4OH-1..4OH+3,
    // cols 4OW-1..4OW+3. Only row -1 (OH==0) / col -1 (OW==0) can be OOB;
    // bottom/right land exactly at 1023. Clamp addr, select 0 after.
    const int gx0 = 4 * OW - 1;   // input col of kx=0, left output
    const int gy0 = 4 * OH - 1;   // input row of ky=0, top output

    const bool colm_ok = (OW > 0);
    const bool row0_ok = (OH > 0);
    const int  gxmc = colm_ok ? gx0 : 0;
    const int  gy0c = row0_ok ? gy0 : 0;

    float a00[C_OUT], a01[C_OUT], a10[C_OUT], a11[C_OUT];
#pragma unroll
    for (int co = 0; co < C_OUT; ++co) {
        a00[co] = 0.0f; a01[co] = 0.0f; a10[co] = 0.0f; a11[co] = 0.0f;
    }

    for (int ci = 0; ci < C_IN; ++ci) {
        const float* xc = xn + (size_t)ci * (IN_H * IN_W);

        // 5x5 window: per row one aligned float4 (cols 4OW..4OW+3; byte
        // offset 16*OW -> 16B aligned) + one scalar (col 4OW-1, clamped).
        float xv[5][5];
#pragma unroll
        for (int r = 0; r < 5; ++r) {
            const int gy = (r == 0) ? gy0c : (gy0 + r);
            const float* xrow = xc + gy * IN_W;
            float4 f4 = *(const float4*)&xrow[gx0 + 1];
            float  sm = xrow[gxmc];
            const bool rok = (r == 0) ? row0_ok : true;  // static true r>=1
            xv[r][0] = (rok && colm_ok) ? sm : 0.0f;
            xv[r][1] = rok ? f4.x : 0.0f;
            xv[r][2] = rok ? f4.y : 0.0f;
            xv[r][3] = rok ? f4.z : 0.0f;
            xv[r][4] = rok ? f4.w : 0.0f;
        }

        // 576 FMAs; wc is thread-uniform -> scalar (SMEM) weight loads,
        // each weight feeds 4 independent acc chains.
        const float* wc = wdec + ci * 9 * C_OUT;
#pragma unroll
        for (int ky = 0; ky < 3; ++ky) {
#pragma unroll
            for (int kx = 0; kx < 3; ++kx) {
                const int t = ky * 3 + kx;
                const float x00 = xv[ky][kx],     x01 = xv[ky][kx + 2];
                const float x10 = xv[ky + 2][kx], x11 = xv[ky + 2][kx + 2];
#pragma unroll
                for (int co = 0; co < C_OUT; ++co) {
                    const float w = wc[t * C_OUT + co];
                    a00[co] = fmaf(w, x00, a00[co]);
                    a01[co] = fmaf(w, x01, a01[co]);
                    a10[co] = fmaf(w, x10, a10[co]);
                    a11[co] = fmaf(w, x11, a11[co]);
                }
            }
        }
    }

    // 2x2 patch -> two float2 stores per co; lanes write 8B each,
    // contiguous across the wave (512B/row/wave).
    const int oh = 2 * OH, ow = 2 * OW;
    float* op = out + (size_t)n * C_OUT * OUT_H * OUT_W
                    + (size_t)oh * OUT_W + ow;
#pragma unroll
    for (int co = 0; co < C_OUT; ++co) {
        float* p = op + (size_t)co * OUT_H * OUT_W;
        *(float2*)(p)         = make_float2(a00[co], a01[co]);
        *(float2*)(p + OUT_W) = make_float2(a10[co], a11[co]);
    }
}

extern "C" void kernel_launch(void* const* d_in, const int* in_sizes, int n_in,
                              void* d_out, int out_size, void* d_ws, size_t ws_size,
                              hipStream_t stream) {
    const float* x = (const float*)d_in[0];
    const float* w = (const float*)d_in[1];
    float* out = (float*)d_out;
    float* wdec = (float*)d_ws;   // 2304 floats = 9216 B

    decode_weights<<<dim3((C_IN * 9 * C_OUT + 255) / 256), dim3(256), 0, stream>>>(w, wdec);

    // block (64,4): 64 col-pairs x 4 row-pairs = 128x8 output tile.
    dim3 block(64, 4, 1);
    dim3 grid(OUT_W / 128, OUT_H / 8, 8);   // (4, 64, 8)
    binconv<<<grid, block, 0, stream>>>(x, wdec, out);
}